// Round 11
// baseline (54.681 us; speedup 1.0000x reference)
//
#include <hip/hip_runtime.h>

// out[b, o*8+n, h, w] = sum_k W[o,k] * x[b, n*32+k, h, w]
// B=32, C=512, HW=3136, 8 windows (stride 32, width 64), W is 64x64 f32.
//
// Round 11: R10 (LDS double-buffer + nt stores) with COUNTED vmcnt at the
// chunk barrier (T4). __syncthreads() drained vmcnt(0) every chunk --
// serializing on the just-issued stage(c+1) AND all 32 stores. Issue order
// per iter is stage(c+1)[8] then stores(c)[32], so `s_waitcnt vmcnt(32)`
// guarantees stage(c+1) + all older stores complete while letting this
// chunk's 32 stores remain in flight; s_barrier then propagates that
// guarantee across waves before buf[c+1] is read / buf[cur] is overwritten.
//
// Fragment mappings (verified rounds 3/5/6/7/8/9/10, absmax 0.0156):
//   A: lane l, elem j holds W[m*32 + (l&31)][si*16 + (l>>5)*8 + j]
//   B: lane l, elem j holds x[ch = n*32 + si*16 + (l>>5)*8 + j][px]
//   C: col = lane&31, row = (r&3) + 8*(r>>2) + 4*(lane>>5)

#define HW   3136
#define CHW  (512 * HW)
#define NCHUNK 14        // 14 x 224 px = 3136

typedef float  f32x16 __attribute__((ext_vector_type(16)));
typedef __bf16 bf16x8 __attribute__((ext_vector_type(8)));

__global__ __launch_bounds__(448) void SKC_65841848648481_kernel(
    const float* __restrict__ x,
    const float* __restrict__ w,
    float* __restrict__ out)
{
    __shared__ float xl[2][64 * 224];       // 2 x 56 KB = 112 KB

    const int tid  = threadIdx.x;
    const int lane = tid & 63;
    const int wv   = tid >> 6;              // wave 0..6 -> 32-px tile in chunk
    const int lc   = lane & 31;
    const int lh   = lane >> 5;

    // Bijective XCD swizzle: 256 ids, 32 contiguous per XCD (256 % 8 == 0)
    // -> each XCD holds 4 full batches; window-overlap re-reads L2-local.
    int id = blockIdx.x;
    id = (id & 7) * 32 + (id >> 3);
    const int n = id & 7;                   // window 0..7
    const int b = id >> 3;                  // batch 0..31

    // ---- W -> A fragments (register-resident) ----
    bf16x8 afrag[2][4];
    #pragma unroll
    for (int m = 0; m < 2; ++m) {
        const float* wr = w + (m * 32 + lc) * 64;
        #pragma unroll
        for (int si = 0; si < 4; ++si) {
            const float4 w0 = *(const float4*)(wr + si * 16 + lh * 8);
            const float4 w1 = *(const float4*)(wr + si * 16 + lh * 8 + 4);
            bf16x8 a;
            a[0] = (__bf16)w0.x; a[1] = (__bf16)w0.y;
            a[2] = (__bf16)w0.z; a[3] = (__bf16)w0.w;
            a[4] = (__bf16)w1.x; a[5] = (__bf16)w1.y;
            a[6] = (__bf16)w1.z; a[7] = (__bf16)w1.w;
            afrag[m][si] = a;
        }
    }

    // ---- staging source pointers: instr q loads float4 at channel
    //      ch = idx/56, px-quad = idx%56 (idx = q*448 + tid); LDS dest
    //      (q*448+tid)*16 bytes == xl[buf][ch][px4*4] (224-f32 rows) ----
    const float* fp[8];
    #pragma unroll
    for (int q = 0; q < 8; ++q) {
        const int idx = q * 448 + tid;      // 0..3583
        const int ch  = idx / 56;
        const int px4 = idx - ch * 56;
        fp[q] = x + (size_t)b * CHW + (size_t)(n * 32 + ch) * HW + px4 * 4;
    }

    float* op = out + (size_t)b * CHW + (size_t)n * HW + wv * 32 + lc;

    // Prologue: stage chunk 0 into buf 0, full drain.
    #pragma unroll
    for (int q = 0; q < 8; ++q) {
        __builtin_amdgcn_global_load_lds(
            (const __attribute__((address_space(1))) void*)(fp[q]),
            (__attribute__((address_space(3))) void*)(&xl[0][(q * 448 + tid) * 4]),
            16, 0, 0);
    }
    asm volatile("s_waitcnt vmcnt(0) lgkmcnt(0)" ::: "memory");
    __builtin_amdgcn_s_barrier();

    for (int c = 0; c < NCHUNK; ++c) {
        const int cur = c & 1;

        // ---- issue stage of chunk c+1 into the other buffer (stays in
        //      flight through this chunk's compute + stores + barrier) ----
        if (c + 1 < NCHUNK) {
            #pragma unroll
            for (int q = 0; q < 8; ++q) {
                __builtin_amdgcn_global_load_lds(
                    (const __attribute__((address_space(1))) void*)(fp[q] + (c + 1) * 224),
                    (__attribute__((address_space(3))) void*)(&xl[cur ^ 1][(q * 448 + tid) * 4]),
                    16, 0, 0);
            }
        }

        // ---- compute this wave's 32-px tile of chunk c ----
        f32x16 acc0, acc1;
        #pragma unroll
        for (int r = 0; r < 16; ++r) { acc0[r] = 0.0f; acc1[r] = 0.0f; }

        #pragma unroll
        for (int si = 0; si < 4; ++si) {
            bf16x8 bf;
            #pragma unroll
            for (int j = 0; j < 8; ++j) {
                const int chl = si * 16 + lh * 8 + j;
                bf[j] = (__bf16)xl[cur][chl * 224 + wv * 32 + lc];  // 2-way bank: free
            }
            acc0 = __builtin_amdgcn_mfma_f32_32x32x16_bf16(afrag[0][si], bf, acc0, 0, 0, 0);
            acc1 = __builtin_amdgcn_mfma_f32_32x32x16_bf16(afrag[1][si], bf, acc1, 0, 0, 0);
        }

        // ---- store chunk c (nontemporal: write-once stream, keep x in L3) ----
        float* os = op + c * 224;
        #pragma unroll
        for (int r = 0; r < 16; ++r) {
            const int row = (r & 3) + 8 * (r >> 2) + 4 * lh;
            __builtin_nontemporal_store(acc0[r], os + (size_t)(row * 8) * HW);
            __builtin_nontemporal_store(acc1[r], os + (size_t)((32 + row) * 8) * HW);
        }

        // ---- counted-vmcnt barrier: newest 32 vmem ops = this chunk's
        //      stores, allowed to stay in flight; everything older (the 8
        //      stage(c+1) loads, prior stores) must have landed. ----
        asm volatile("s_waitcnt vmcnt(32) lgkmcnt(0)" ::: "memory");
        __builtin_amdgcn_s_barrier();
    }
}

extern "C" void kernel_launch(void* const* d_in, const int* in_sizes, int n_in,
                              void* d_out, int out_size, void* d_ws, size_t ws_size,
                              hipStream_t stream)
{
    const float* x  = (const float*)d_in[0];   // (32, 512, 56, 56) f32
    const float* w  = (const float*)d_in[1];   // (64, 64) f32
    float* out      = (float*)d_out;           // (32, 512, 56, 56) f32

    dim3 grid(256);    // 8 windows x 32 batches = 1 block/CU
    dim3 block(448);   // 7 waves, one 32-px tile each per chunk
    hipLaunchKernelGGL(SKC_65841848648481_kernel, grid, block, 0, stream,
                       x, w, out);
}